// Round 1
// 795.385 us; speedup vs baseline: 1.5878x; 1.5878x over previous
//
#include <hip/hip_runtime.h>
#include <hip/hip_bf16.h>

// ---------------------------------------------------------------------------
// WindowAttention (Swin-style), MI355X / gfx950
//   x:(2048,49,512) f32  -> qkv GEMM (bf16 MFMA) -> per-(b,h) attention (MFMA)
//   -> proj GEMM (bf16 MFMA) -> out f32
// ---------------------------------------------------------------------------

typedef __bf16  bf16x8 __attribute__((ext_vector_type(8)));
typedef float   f32x4  __attribute__((ext_vector_type(4)));

#define B_TOT   2048
#define NTOK    49
#define CDIM    512
#define NHEAD   16
#define HDIM    32
#define MROWS   (B_TOT * NTOK)      // 100352
#define QKVN    (3 * CDIM)          // 1536

// ---- async global->LDS ------------------------------------------------------
__device__ __forceinline__ void load_lds16(const void* gptr, void* lptr) {
    __builtin_amdgcn_global_load_lds(
        (const __attribute__((address_space(1))) unsigned int*)gptr,
        (__attribute__((address_space(3))) unsigned int*)lptr,
        16, 0, 0);
}
__device__ __forceinline__ void load_lds4(const void* gptr, void* lptr) {
    __builtin_amdgcn_global_load_lds(
        (const __attribute__((address_space(1))) unsigned int*)gptr,
        (__attribute__((address_space(3))) unsigned int*)lptr,
        4, 0, 0);
}

// ---- fp32 -> bf16 convert (vectorized, n multiple of 4) --------------------
__global__ void cvt_f32_bf16(const float* __restrict__ in,
                             __hip_bfloat16* __restrict__ out, int n4) {
    int idx = blockIdx.x * blockDim.x + threadIdx.x;
    int stride = gridDim.x * blockDim.x;
    for (int i = idx; i < n4; i += stride) {
        float4 f = ((const float4*)in)[i];
        union { __hip_bfloat16 h[4]; ushort4 u; } c;
        c.h[0] = __float2bfloat16(f.x);
        c.h[1] = __float2bfloat16(f.y);
        c.h[2] = __float2bfloat16(f.z);
        c.h[3] = __float2bfloat16(f.w);
        ((ushort4*)out)[i] = c.u;
    }
}

// ---- C = A @ B^T + bias : A (M,K) bf16 rm, B (N,K) bf16 rm -----------------
template <typename OutT>
__global__ __launch_bounds__(256) void gemm_bt(
    const __hip_bfloat16* __restrict__ A,
    const __hip_bfloat16* __restrict__ B,
    const float* __restrict__ bias,
    OutT* __restrict__ C,
    int M, int N, int K)
{
    __shared__ __align__(16) __hip_bfloat16 As[128 * 32];
    __shared__ __align__(16) __hip_bfloat16 Bs[128 * 32];

    const int tid  = threadIdx.x;
    const int lane = tid & 63;
    const int wave = tid >> 6;
    const int wm   = (wave >> 1) * 64;
    const int wn   = (wave & 1) * 64;
    const int quad = lane >> 4;
    const int l16  = lane & 15;

    const int m0 = blockIdx.y * 128;
    const int n0 = blockIdx.x * 128;

    const int off0 = tid * 8;             // elems
    const int off1 = (256 + tid) * 8;
    const int r0 = off0 >> 5, c0 = off0 & 31;
    const int r1 = off1 >> 5, c1 = off1 & 31;

    const __hip_bfloat16* Ab = A + (long)m0 * K;
    const __hip_bfloat16* Bb = B + (long)n0 * K;

    f32x4 acc[4][4] = {};

    for (int k0 = 0; k0 < K; k0 += 32) {
        load_lds16(Ab + (long)r0 * K + k0 + c0, &As[off0]);
        load_lds16(Ab + (long)r1 * K + k0 + c1, &As[off1]);
        load_lds16(Bb + (long)r0 * K + k0 + c0, &Bs[off0]);
        load_lds16(Bb + (long)r1 * K + k0 + c1, &Bs[off1]);
        __syncthreads();

        bf16x8 a[4], b[4];
#pragma unroll
        for (int i = 0; i < 4; ++i)
            a[i] = *(const bf16x8*)&As[(wm + i * 16 + l16) * 32 + quad * 8];
#pragma unroll
        for (int j = 0; j < 4; ++j)
            b[j] = *(const bf16x8*)&Bs[(wn + j * 16 + l16) * 32 + quad * 8];
#pragma unroll
        for (int i = 0; i < 4; ++i)
#pragma unroll
            for (int j = 0; j < 4; ++j)
                acc[i][j] = __builtin_amdgcn_mfma_f32_16x16x32_bf16(
                    a[i], b[j], acc[i][j], 0, 0, 0);
        __syncthreads();
    }

#pragma unroll
    for (int i = 0; i < 4; ++i) {
#pragma unroll
        for (int j = 0; j < 4; ++j) {
            const int col = n0 + wn + j * 16 + l16;
            const float bv = bias[col];
#pragma unroll
            for (int r = 0; r < 4; ++r) {
                const int row = m0 + wm + i * 16 + quad * 4 + r;
                const float val = acc[i][j][r] + bv;
                if constexpr (sizeof(OutT) == 2)
                    C[(long)row * N + col] = __float2bfloat16(val);
                else
                    C[(long)row * N + col] = val;
            }
        }
    }
}

// ---------------------------------------------------------------------------
// MFMA window attention. 1 block = 4 waves = heads hq*4..hq*4+3 of batch b.
// Swapped QK^T (S^T = mfma(K,Q)) so softmax-over-keys is lane-local + 2 shfl.
// P (normalized, bf16, XOR-swizzled) aliases the dead Q/K LDS tiles.
// LDS byte map:
//   [0)      Q   49x(4 heads x 32) bf16, row 256B, col-swizzled   (12544)
//   [12544)  K   same                                             (12544)
//   [25088)  V   64 rows (49 real + 15 zero pad)                  (16384)
//   [41472)  bias bf16 [4 heads][169]                             ( 1352)
//   [42824)  mask f32 [2401]                                      ( 9604)
// P (per wave w): [0) + w*6272, rows q<49 x 128B, byte ^= (q&7)<<4
// ---------------------------------------------------------------------------
#define QS_OFF   0
#define KS_OFF   12544
#define VS_OFF   25088
#define BIAS_OFF 41472
#define MASK_OFF 42824
#define SMEM_BYTES 52432

__global__ __launch_bounds__(256) void attn_mfma(
    const __hip_bfloat16* __restrict__ qkv,
    const float* __restrict__ mask,        // (64, 49, 49)
    const float* __restrict__ bias_table,  // (169, 16)
    __hip_bfloat16* __restrict__ out)
{
    __shared__ __align__(16) char smem[SMEM_BYTES];

    const int tid  = threadIdx.x;
    const int lane = tid & 63;
    const int w    = tid >> 6;        // wave -> head offset
    const int l16  = lane & 15;
    const int quad = lane >> 4;
    const int b    = blockIdx.x >> 2;
    const int hq   = blockIdx.x & 3;  // head-quad: heads hq*4 .. hq*4+3

    // ---- stage Q,K,V (pre-swizzled global source -> linear LDS dest) ------
    {
        const long rowbase = (long)b * NTOK * QKVN;
        for (int e = tid; e < 2352; e += 256) {          // 3 mats * 49 tok * 16 segs
            const int m   = e / 784;
            const int rr  = e - m * 784;
            const int tok = rr >> 4, seg = rr & 15;
            const int segl = seg ^ (tok & 7);            // inverse swizzle on source
            const __hip_bfloat16* src =
                qkv + rowbase + (long)tok * QKVN + m * 512 + hq * 128 + segl * 8;
            load_lds16(src, smem + e * 16);
        }
        // zero V pad rows 49..63 (so p=0 * garbage never makes NaN)
        for (int e = tid; e < 960; e += 256)
            ((unsigned int*)(smem + VS_OFF + 49 * 256))[e] = 0u;
        // mask window, raw f32
        const float* msrc = mask + (long)(b & 63) * (NTOK * NTOK);
        for (int e = tid; e < NTOK * NTOK; e += 256)
            load_lds4(msrc + e, smem + MASK_OFF + e * 4);
        // per-head bias rows, bf16
        __hip_bfloat16* sb = (__hip_bfloat16*)(smem + BIAS_OFF);
        for (int e = tid; e < 676; e += 256) {
            const int w2 = e / 169, rel = e - w2 * 169;
            sb[e] = __float2bfloat16(bias_table[rel * NHEAD + hq * 4 + w2]);
        }
    }
    __syncthreads();

    // ---- S^T = K Q^T  (rows = keys, cols = queries) ------------------------
    const int fro = (w * 64 + quad * 16) ^ ((l16 & 7) << 4);  // swizzled frag offset
    bf16x8 af[4], bf[4];
#pragma unroll
    for (int t = 0; t < 4; ++t) {
        const int tok = t * 16 + l16;                    // rows >=49 read garbage; masked later
        af[t] = *(const bf16x8*)(smem + KS_OFF + tok * 256 + fro);
        bf[t] = *(const bf16x8*)(smem + QS_OFF + tok * 256 + fro);
    }
    f32x4 acc[4][4] = {};
#pragma unroll
    for (int i = 0; i < 4; ++i)
#pragma unroll
        for (int j = 0; j < 4; ++j)
            acc[i][j] = __builtin_amdgcn_mfma_f32_16x16x32_bf16(
                af[i], bf[j], acc[i][j], 0, 0, 0);
    __syncthreads();   // Q/K tiles now dead -> P may alias them

    // ---- softmax over keys, per query column -------------------------------
    const float scale = 0.17677669529663687f;  // 1/sqrt(32)
    const float* smf = (const float*)(smem + MASK_OFF);
    const __hip_bfloat16* sb = (const __hip_bfloat16*)(smem + BIAS_OFF);
    const int quad4 = quad * 4;

    // rel(q,k) = (ri-rj+6)*13 + (ci-cj+6) = qp(q) + kp(k)  -- separable
    int kp[4][4];
#pragma unroll
    for (int i = 0; i < 4; ++i)
#pragma unroll
        for (int r = 0; r < 4; ++r) {
            const int k  = i * 16 + quad4 + r;
            const int rj = k / 7, cj = k - rj * 7;
            kp[i][r] = (6 - rj) * 13 + (6 - cj);
        }

    char* pbase = smem + w * 6272;   // aliases Q/K region, per-wave slab
#pragma unroll
    for (int j = 0; j < 4; ++j) {
        const int q   = j * 16 + l16;
        const bool qok = q < NTOK;
        const int ri  = q / 7, ci = q - ri * 7;
        const int qp  = ri * 13 + ci;
        const int mrow = q * NTOK;
        float mx = -1e30f;
#pragma unroll
        for (int i = 0; i < 4; ++i)
#pragma unroll
            for (int r = 0; r < 4; ++r) {
                const int k = i * 16 + quad4 + r;
                float v;
                if (qok && k < NTOK) {
                    v = fmaf(acc[i][j][r], scale,
                             __bfloat162float(sb[w * 169 + qp + kp[i][r]]) + smf[mrow + k]);
                } else {
                    v = -1e30f;     // overwrite (not add): kills any pad NaN
                }
                acc[i][j][r] = v;
                mx = fmaxf(mx, v);
            }
        mx = fmaxf(mx, __shfl_xor(mx, 16));
        mx = fmaxf(mx, __shfl_xor(mx, 32));
        float s = 0.f;
#pragma unroll
        for (int i = 0; i < 4; ++i)
#pragma unroll
            for (int r = 0; r < 4; ++r) {
                const float ev = __expf(acc[i][j][r] - mx);
                acc[i][j][r] = ev;
                s += ev;
            }
        s += __shfl_xor(s, 16);
        s += __shfl_xor(s, 32);
        const float inv = 1.0f / s;
        if (qok) {
            char* prow = pbase + q * 128;
            const int xr = (q & 7) << 4;
#pragma unroll
            for (int i = 0; i < 4; ++i) {
                union { __hip_bfloat16 h[4]; uint2 u; } pk;
#pragma unroll
                for (int r = 0; r < 4; ++r)
                    pk.h[r] = __float2bfloat16(acc[i][j][r] * inv);
                *(uint2*)(prow + ((i * 32 + quad * 8) ^ xr)) = pk.u;
            }
        }
    }
    __syncthreads();   // P visible to all lanes of the wave (and cheap safety)

    // ---- O = P V ------------------------------------------------------------
    bf16x8 pa[4][2];               // [q-tile][k-step]
#pragma unroll
    for (int mt = 0; mt < 4; ++mt) {
        const int q  = mt * 16 + l16;
        const int xr = (q & 7) << 4;
#pragma unroll
        for (int ks = 0; ks < 2; ++ks)
            pa[mt][ks] = *(const bf16x8*)(pbase + q * 128 + ((ks * 64 + quad * 16) ^ xr));
    }
    bf16x8 vb[2][2];               // [d-tile][k-step]  (column reads of V)
#pragma unroll
    for (int dt = 0; dt < 2; ++dt)
#pragma unroll
        for (int ks = 0; ks < 2; ++ks)
#pragma unroll
            for (int e = 0; e < 8; ++e) {
                const int key = ks * 32 + quad * 8 + e;         // key&7 == e
                const int dby = (w * 32 + dt * 16 + l16) * 2;
                vb[dt][ks][e] = *(const __bf16*)(smem + VS_OFF + key * 256 + (dby ^ (e << 4)));
            }
    f32x4 o[4][2] = {};
#pragma unroll
    for (int mt = 0; mt < 4; ++mt)
#pragma unroll
        for (int dt = 0; dt < 2; ++dt)
#pragma unroll
            for (int ks = 0; ks < 2; ++ks)
                o[mt][dt] = __builtin_amdgcn_mfma_f32_16x16x32_bf16(
                    pa[mt][ks], vb[dt][ks], o[mt][dt], 0, 0, 0);

    // ---- store: out[b*49+q][hq*128 + w*32 + d] -----------------------------
    const long obase = (long)b * NTOK * CDIM + hq * 128 + w * 32;
#pragma unroll
    for (int mt = 0; mt < 4; ++mt)
#pragma unroll
        for (int r = 0; r < 4; ++r) {
            const int q = mt * 16 + quad4 + r;
            if (q < NTOK) {
                const long rb = obase + (long)q * CDIM;
#pragma unroll
                for (int dt = 0; dt < 2; ++dt)
                    out[rb + dt * 16 + l16] = __float2bfloat16(o[mt][dt][r]);
            }
        }
}

// ---------------------------------------------------------------------------
extern "C" void kernel_launch(void* const* d_in, const int* in_sizes, int n_in,
                              void* d_out, int out_size, void* d_ws, size_t ws_size,
                              hipStream_t stream) {
    const float* x          = (const float*)d_in[0];
    const float* mask       = (const float*)d_in[1];
    const float* qkv_w      = (const float*)d_in[2];
    const float* qkv_b      = (const float*)d_in[3];
    const float* proj_w     = (const float*)d_in[4];
    const float* proj_b     = (const float*)d_in[5];
    const float* bias_table = (const float*)d_in[6];

    char* ws = (char*)d_ws;
    __hip_bfloat16* xb   = (__hip_bfloat16*)(ws);
    __hip_bfloat16* qw   = (__hip_bfloat16*)(ws + 102760448);
    __hip_bfloat16* pw   = (__hip_bfloat16*)(ws + 104333312);
    __hip_bfloat16* qkvb = (__hip_bfloat16*)(ws + 104857600);
    __hip_bfloat16* ao   = xb;  // attn out reuses x_bf16 (GEMM1 done by then)

    cvt_f32_bf16<<<32768, 256, 0, stream>>>(x, xb, (MROWS * CDIM) / 4);
    cvt_f32_bf16<<<768,   256, 0, stream>>>(qkv_w, qw, (QKVN * CDIM) / 4);
    cvt_f32_bf16<<<256,   256, 0, stream>>>(proj_w, pw, (CDIM * CDIM) / 4);

    gemm_bt<__hip_bfloat16><<<dim3(QKVN / 128, MROWS / 128), 256, 0, stream>>>(
        xb, qw, qkv_b, qkvb, MROWS, QKVN, CDIM);

    attn_mfma<<<B_TOT * 4, 256, 0, stream>>>(qkvb, mask, bias_table, ao);

    gemm_bt<float><<<dim3(CDIM / 128, MROWS / 128), 256, 0, stream>>>(
        ao, pw, proj_b, (float*)d_out, MROWS, CDIM, CDIM);
}

// Round 2
// 774.173 us; speedup vs baseline: 1.6313x; 1.0274x over previous
//
#include <hip/hip_runtime.h>
#include <hip/hip_bf16.h>

// ---------------------------------------------------------------------------
// WindowAttention (Swin-style), MI355X / gfx950
//   x:(2048,49,512) f32 -> qkv GEMM (256^2 8-phase bf16 MFMA) -> attention
//   (MFMA) -> proj GEMM -> out f32
// ---------------------------------------------------------------------------

typedef __bf16  bf16x8 __attribute__((ext_vector_type(8)));
typedef float   f32x4  __attribute__((ext_vector_type(4)));

#define B_TOT   2048
#define NTOK    49
#define CDIM    512
#define NHEAD   16
#define HDIM    32
#define MROWS   (B_TOT * NTOK)      // 100352
#define QKVN    (3 * CDIM)          // 1536

// ---- async global->LDS ------------------------------------------------------
__device__ __forceinline__ void load_lds16(const void* gptr, void* lptr) {
    __builtin_amdgcn_global_load_lds(
        (const __attribute__((address_space(1))) unsigned int*)gptr,
        (__attribute__((address_space(3))) unsigned int*)lptr,
        16, 0, 0);
}
__device__ __forceinline__ void load_lds4(const void* gptr, void* lptr) {
    __builtin_amdgcn_global_load_lds(
        (const __attribute__((address_space(1))) unsigned int*)gptr,
        (__attribute__((address_space(3))) unsigned int*)lptr,
        4, 0, 0);
}

// ---- fp32 -> bf16 convert (vectorized) -------------------------------------
__global__ void cvt_f32_bf16(const float* __restrict__ in,
                             __hip_bfloat16* __restrict__ out, int n4) {
    int idx = blockIdx.x * blockDim.x + threadIdx.x;
    int stride = gridDim.x * blockDim.x;
    for (int i = idx; i < n4; i += stride) {
        float4 f = ((const float4*)in)[i];
        union { __hip_bfloat16 h[4]; ushort4 u; } c;
        c.h[0] = __float2bfloat16(f.x);
        c.h[1] = __float2bfloat16(f.y);
        c.h[2] = __float2bfloat16(f.z);
        c.h[3] = __float2bfloat16(f.w);
        ((ushort4*)out)[i] = c.u;
    }
}

// ---------------------------------------------------------------------------
// 256x256 deep-pipelined GEMM, C = A @ B^T + bias.
// A (M,K) bf16 rm, B (N,K) bf16 rm. M%256==0, N%256==0, K%128==0.
// 8 waves (2M x 4N), per-wave 128x64 output, BK=64 split in two K-halves.
// LDS: A[2 dbuf][2 kk][256 rows][32 cols] bf16 (64KB) + B same (64KB).
// K-half-major layout => 64B rows => frag ds_read_b128 is bank-uniform
// (8 lanes per bank-column = b128 floor) -- no swizzle needed.
// Staging runs 6 phases ahead of consumption:
//   tile t: ph0 issues A-K1(t+1), ph1: B-K1(t+1), ph2: A-K0(t+2), ph3: B-K0(t+2)
// => end-of-phase waits are vmcnt(8): 4-6 loads ALWAYS in flight across
// barriers (counted vmcnt, never 0 in main loop). Soundness: per-wave loads
// are issued in fixed order; vmcnt(8) with 12 outstanding guards exactly the
// 2 oldest half-tiles, which are the ones consumed next; vmcnt precedes the
// barrier so completion is published to all waves.
// ---------------------------------------------------------------------------
#define BARR    asm volatile("s_barrier" ::: "memory")
#define WAITV(N) asm volatile("s_waitcnt vmcnt(" #N ")" ::: "memory")
#define MFMA16(av, bv, cv) __builtin_amdgcn_mfma_f32_16x16x32_bf16(av, bv, cv, 0, 0, 0)

template <typename OutT>
__global__ __launch_bounds__(512, 2) void gemm256(
    const __hip_bfloat16* __restrict__ A,
    const __hip_bfloat16* __restrict__ B,
    const float* __restrict__ bias,
    OutT* __restrict__ C,
    int M, int N, int K, int nbx, int cpx)
{
    extern __shared__ __align__(16) char smem[];
    char* sA = smem;
    char* sB = smem + 65536;

    const int NT = K >> 6;           // K-tiles of 64 (>=2 assumed; here 8)

    const int tid  = threadIdx.x;
    const int lane = tid & 63;
    const int wave = tid >> 6;
    const int wm   = wave >> 2;      // 0..1
    const int wn   = wave & 3;       // 0..3
    const int l16  = lane & 15;
    const int quad = lane >> 4;

    // bijective XCD swizzle (gridDim %8==0), n-block fastest within chunk
    const int id = blockIdx.x;
    const int sw = (id & 7) * cpx + (id >> 3);
    const int mb = sw / nbx;
    const int nb = sw - mb * nbx;
    const int m0 = mb << 8;
    const int n0 = nb << 8;

    // staging: thread -> (row = tid>>2 [+128 for 2nd load], chunk = tid&3)
    const int r  = tid >> 2;
    const int ch = tid & 3;
    const __hip_bfloat16* Ag0 = A + (size_t)(m0 + r) * K + ch * 8;
    const __hip_bfloat16* Ag1 = Ag0 + (size_t)128 * K;
    const __hip_bfloat16* Bg0 = B + (size_t)(n0 + r) * K + ch * 8;
    const __hip_bfloat16* Bg1 = Bg0 + (size_t)128 * K;
    char* dA = sA + tid * 16;
    char* dB = sB + tid * 16;

#define STAGE_A(t2, kh) \
    { load_lds16(Ag0 + (t2) * 64 + (kh) * 32, dA + ((t2) & 1) * 32768 + (kh) * 16384);        \
      load_lds16(Ag1 + (t2) * 64 + (kh) * 32, dA + ((t2) & 1) * 32768 + (kh) * 16384 + 8192); }
#define STAGE_B(t2, kh) \
    { load_lds16(Bg0 + (t2) * 64 + (kh) * 32, dB + ((t2) & 1) * 32768 + (kh) * 16384);        \
      load_lds16(Bg1 + (t2) * 64 + (kh) * 32, dB + ((t2) & 1) * 32768 + (kh) * 16384 + 8192); }

    // prologue: issue 6 half-tiles in consumption order; keep last 4 in flight
    STAGE_A(0, 0); STAGE_B(0, 0);
    STAGE_A(0, 1); STAGE_B(0, 1);
    STAGE_A(1, 0); STAGE_B(1, 0);
    WAITV(8);                         // A-K0(0), B-K0(0) landed
    BARR;

    const int tA = (wm * 128 + l16) * 64 + quad * 16;  // frag base (bytes)
    const int tB = (wn * 64  + l16) * 64 + quad * 16;

    f32x4 acc[8][4] = {};
    bf16x8 a[8], b[2];

#pragma unroll 2
    for (int t = 0; t < NT; ++t) {
        const int sl = (t & 1) * 32768;
        const char* pA0 = sA + sl;            // kk = 0
        const char* pB0 = sB + sl;
        const char* pA1 = sA + sl + 16384;    // kk = 1
        const char* pB1 = sB + sl + 16384;

        // ---- ph0: kk=0, nh=0 -------------------------------------------
#pragma unroll
        for (int i = 0; i < 8; ++i) a[i] = *(const bf16x8*)(pA0 + tA + i * 1024);
        b[0] = *(const bf16x8*)(pB0 + tB);
        b[1] = *(const bf16x8*)(pB0 + tB + 1024);
        if (t + 1 < NT) STAGE_A(t + 1, 1);
        BARR;
        __builtin_amdgcn_s_setprio(1);
#pragma unroll
        for (int i = 0; i < 8; ++i) {
            acc[i][0] = MFMA16(a[i], b[0], acc[i][0]);
            acc[i][1] = MFMA16(a[i], b[1], acc[i][1]);
        }
        __builtin_amdgcn_s_setprio(0);
        BARR;

        // ---- ph1: kk=0, nh=1 (reuse a) ---------------------------------
        b[0] = *(const bf16x8*)(pB0 + tB + 2048);
        b[1] = *(const bf16x8*)(pB0 + tB + 3072);
        if (t + 1 < NT) STAGE_B(t + 1, 1);
        BARR;
        __builtin_amdgcn_s_setprio(1);
#pragma unroll
        for (int i = 0; i < 8; ++i) {
            acc[i][2] = MFMA16(a[i], b[0], acc[i][2]);
            acc[i][3] = MFMA16(a[i], b[1], acc[i][3]);
        }
        __builtin_amdgcn_s_setprio(0);
        if (t < NT - 1) { WAITV(8); } else { WAITV(0); }   // guard K1(t)
        BARR;

        // ---- ph2: kk=1, nh=0 -------------------------------------------
#pragma unroll
        for (int i = 0; i < 8; ++i) a[i] = *(const bf16x8*)(pA1 + tA + i * 1024);
        b[0] = *(const bf16x8*)(pB1 + tB);
        b[1] = *(const bf16x8*)(pB1 + tB + 1024);
        if (t + 2 < NT) STAGE_A(t + 2, 0);
        BARR;
        __builtin_amdgcn_s_setprio(1);
#pragma unroll
        for (int i = 0; i < 8; ++i) {
            acc[i][0] = MFMA16(a[i], b[0], acc[i][0]);
            acc[i][1] = MFMA16(a[i], b[1], acc[i][1]);
        }
        __builtin_amdgcn_s_setprio(0);
        BARR;

        // ---- ph3: kk=1, nh=1 -------------------------------------------
        b[0] = *(const bf16x8*)(pB1 + tB + 2048);
        b[1] = *(const bf16x8*)(pB1 + tB + 3072);
        if (t + 2 < NT) STAGE_B(t + 2, 0);
        BARR;
        __builtin_amdgcn_s_setprio(1);
#pragma unroll
        for (int i = 0; i < 8; ++i) {
            acc[i][2] = MFMA16(a[i], b[0], acc[i][2]);
            acc[i][3] = MFMA16(a[i], b[1], acc[i][3]);
        }
        __builtin_amdgcn_s_setprio(0);
        if (t < NT - 2) { WAITV(8); }            // guard K0(t+1)
        else if (t == NT - 2) { WAITV(4); }      // tail: only K1(NT-1) in flight
        BARR;
    }
#undef STAGE_A
#undef STAGE_B

    // epilogue: D row = quad*4+r, col = l16 (verified layout)
#pragma unroll
    for (int i = 0; i < 8; ++i) {
#pragma unroll
        for (int jj = 0; jj < 4; ++jj) {
            const int col = n0 + wn * 64 + jj * 16 + l16;
            const float bv = bias[col];
#pragma unroll
            for (int rr = 0; rr < 4; ++rr) {
                const int row = m0 + wm * 128 + i * 16 + quad * 4 + rr;
                const float val = acc[i][jj][rr] + bv;
                if constexpr (sizeof(OutT) == 2)
                    C[(size_t)row * N + col] = __float2bfloat16(val);
                else
                    C[(size_t)row * N + col] = val;
            }
        }
    }
}

// ---------------------------------------------------------------------------
// MFMA window attention. 1 block = 4 waves = heads hq*4..hq*4+3 of batch b.
// (unchanged from previous round)
// ---------------------------------------------------------------------------
#define QS_OFF   0
#define KS_OFF   12544
#define VS_OFF   25088
#define BIAS_OFF 41472
#define MASK_OFF 42824
#define SMEM_BYTES 52432

__global__ __launch_bounds__(256) void attn_mfma(
    const __hip_bfloat16* __restrict__ qkv,
    const float* __restrict__ mask,        // (64, 49, 49)
    const float* __restrict__ bias_table,  // (169, 16)
    __hip_bfloat16* __restrict__ out)
{
    __shared__ __align__(16) char smem[SMEM_BYTES];

    const int tid  = threadIdx.x;
    const int lane = tid & 63;
    const int w    = tid >> 6;
    const int l16  = lane & 15;
    const int quad = lane >> 4;
    const int b    = blockIdx.x >> 2;
    const int hq   = blockIdx.x & 3;

    {
        const long rowbase = (long)b * NTOK * QKVN;
        for (int e = tid; e < 2352; e += 256) {
            const int m   = e / 784;
            const int rr  = e - m * 784;
            const int tok = rr >> 4, seg = rr & 15;
            const int segl = seg ^ (tok & 7);
            const __hip_bfloat16* src =
                qkv + rowbase + (long)tok * QKVN + m * 512 + hq * 128 + segl * 8;
            load_lds16(src, smem + e * 16);
        }
        for (int e = tid; e < 960; e += 256)
            ((unsigned int*)(smem + VS_OFF + 49 * 256))[e] = 0u;
        const float* msrc = mask + (long)(b & 63) * (NTOK * NTOK);
        for (int e = tid; e < NTOK * NTOK; e += 256)
            load_lds4(msrc + e, smem + MASK_OFF + e * 4);
        __hip_bfloat16* sb = (__hip_bfloat16*)(smem + BIAS_OFF);
        for (int e = tid; e < 676; e += 256) {
            const int w2 = e / 169, rel = e - w2 * 169;
            sb[e] = __float2bfloat16(bias_table[rel * NHEAD + hq * 4 + w2]);
        }
    }
    __syncthreads();

    const int fro = (w * 64 + quad * 16) ^ ((l16 & 7) << 4);
    bf16x8 af[4], bf[4];
#pragma unroll
    for (int t = 0; t < 4; ++t) {
        const int tok = t * 16 + l16;
        af[t] = *(const bf16x8*)(smem + KS_OFF + tok * 256 + fro);
        bf[t] = *(const bf16x8*)(smem + QS_OFF + tok * 256 + fro);
    }
    f32x4 acc[4][4] = {};
#pragma unroll
    for (int i = 0; i < 4; ++i)
#pragma unroll
        for (int j = 0; j < 4; ++j)
            acc[i][j] = __builtin_amdgcn_mfma_f32_16x16x32_bf16(
                af[i], bf[j], acc[i][j], 0, 0, 0);
    __syncthreads();

    const float scale = 0.17677669529663687f;
    const float* smf = (const float*)(smem + MASK_OFF);
    const __hip_bfloat16* sb = (const __hip_bfloat16*)(smem + BIAS_OFF);
    const int quad4 = quad * 4;

    int kp[4][4];
#pragma unroll
    for (int i = 0; i < 4; ++i)
#pragma unroll
        for (int r = 0; r < 4; ++r) {
            const int k  = i * 16 + quad4 + r;
            const int rj = k / 7, cj = k - rj * 7;
            kp[i][r] = (6 - rj) * 13 + (6 - cj);
        }

    char* pbase = smem + w * 6272;
#pragma unroll
    for (int j = 0; j < 4; ++j) {
        const int q   = j * 16 + l16;
        const bool qok = q < NTOK;
        const int ri  = q / 7, ci = q - ri * 7;
        const int qp  = ri * 13 + ci;
        const int mrow = q * NTOK;
        float mx = -1e30f;
#pragma unroll
        for (int i = 0; i < 4; ++i)
#pragma unroll
            for (int r = 0; r < 4; ++r) {
                const int k = i * 16 + quad4 + r;
                float v;
                if (qok && k < NTOK) {
                    v = fmaf(acc[i][j][r], scale,
                             __bfloat162float(sb[w * 169 + qp + kp[i][r]]) + smf[mrow + k]);
                } else {
                    v = -1e30f;
                }
                acc[i][j][r] = v;
                mx = fmaxf(mx, v);
            }
        mx = fmaxf(mx, __shfl_xor(mx, 16));
        mx = fmaxf(mx, __shfl_xor(mx, 32));
        float s = 0.f;
#pragma unroll
        for (int i = 0; i < 4; ++i)
#pragma unroll
            for (int r = 0; r < 4; ++r) {
                const float ev = __expf(acc[i][j][r] - mx);
                acc[i][j][r] = ev;
                s += ev;
            }
        s += __shfl_xor(s, 16);
        s += __shfl_xor(s, 32);
        const float inv = 1.0f / s;
        if (qok) {
            char* prow = pbase + q * 128;
            const int xr = (q & 7) << 4;
#pragma unroll
            for (int i = 0; i < 4; ++i) {
                union { __hip_bfloat16 h[4]; uint2 u; } pk;
#pragma unroll
                for (int r = 0; r < 4; ++r)
                    pk.h[r] = __float2bfloat16(acc[i][j][r] * inv);
                *(uint2*)(prow + ((i * 32 + quad * 8) ^ xr)) = pk.u;
            }
        }
    }
    __syncthreads();

    bf16x8 pa[4][2];
#pragma unroll
    for (int mt = 0; mt < 4; ++mt) {
        const int q  = mt * 16 + l16;
        const int xr = (q & 7) << 4;
#pragma unroll
        for (int ks = 0; ks < 2; ++ks)
            pa[mt][ks] = *(const bf16x8*)(pbase + q * 128 + ((ks * 64 + quad * 16) ^ xr));
    }
    bf16x8 vb[2][2];
#pragma unroll
    for (int dt = 0; dt < 2; ++dt)
#pragma unroll
        for (int ks = 0; ks < 2; ++ks)
#pragma unroll
            for (int e = 0; e < 8; ++e) {
                const int key = ks * 32 + quad * 8 + e;
                const int dby = (w * 32 + dt * 16 + l16) * 2;
                vb[dt][ks][e] = *(const __bf16*)(smem + VS_OFF + key * 256 + (dby ^ (e << 4)));
            }
    f32x4 o[4][2] = {};
#pragma unroll
    for (int mt = 0; mt < 4; ++mt)
#pragma unroll
        for (int dt = 0; dt < 2; ++dt)
#pragma unroll
            for (int ks = 0; ks < 2; ++ks)
                o[mt][dt] = __builtin_amdgcn_mfma_f32_16x16x32_bf16(
                    pa[mt][ks], vb[dt][ks], o[mt][dt], 0, 0, 0);

    const long obase = (long)b * NTOK * CDIM + hq * 128 + w * 32;
#pragma unroll
    for (int mt = 0; mt < 4; ++mt)
#pragma unroll
        for (int r = 0; r < 4; ++r) {
            const int q = mt * 16 + quad4 + r;
            if (q < NTOK) {
                const long rb = obase + (long)q * CDIM;
#pragma unroll
                for (int dt = 0; dt < 2; ++dt)
                    out[rb + dt * 16 + l16] = __float2bfloat16(o[mt][dt][r]);
            }
        }
}

// ---------------------------------------------------------------------------
extern "C" void kernel_launch(void* const* d_in, const int* in_sizes, int n_in,
                              void* d_out, int out_size, void* d_ws, size_t ws_size,
                              hipStream_t stream) {
    const float* x          = (const float*)d_in[0];
    const float* mask       = (const float*)d_in[1];
    const float* qkv_w      = (const float*)d_in[2];
    const float* qkv_b      = (const float*)d_in[3];
    const float* proj_w     = (const float*)d_in[4];
    const float* proj_b     = (const float*)d_in[5];
    const float* bias_table = (const float*)d_in[6];

    char* ws = (char*)d_ws;
    __hip_bfloat16* xb   = (__hip_bfloat16*)(ws);
    __hip_bfloat16* qw   = (__hip_bfloat16*)(ws + 102760448);
    __hip_bfloat16* pw   = (__hip_bfloat16*)(ws + 104333312);
    __hip_bfloat16* qkvb = (__hip_bfloat16*)(ws + 104857600);
    __hip_bfloat16* ao   = xb;  // attn out reuses x_bf16 (GEMM1 done by then)

    static int attr_done = 0;
    if (!attr_done) {
        hipFuncSetAttribute(
            reinterpret_cast<const void*>(&gemm256<__hip_bfloat16>),
            hipFuncAttributeMaxDynamicSharedMemorySize, 131072);
        hipFuncSetAttribute(
            reinterpret_cast<const void*>(&gemm256<float>),
            hipFuncAttributeMaxDynamicSharedMemorySize, 131072);
        attr_done = 1;
    }

    cvt_f32_bf16<<<32768, 256, 0, stream>>>(x, xb, (MROWS * CDIM) / 4);
    cvt_f32_bf16<<<768,   256, 0, stream>>>(qkv_w, qw, (QKVN * CDIM) / 4);
    cvt_f32_bf16<<<256,   256, 0, stream>>>(proj_w, pw, (CDIM * CDIM) / 4);

    // qkv: M=100352, N=1536, K=512 -> 392*6 = 2352 blocks (%8==0)
    gemm256<__hip_bfloat16><<<2352, 512, 131072, stream>>>(
        xb, qw, qkv_b, qkvb, MROWS, QKVN, CDIM, 6, 294);

    attn_mfma<<<B_TOT * 4, 256, 0, stream>>>(qkvb, mask, bias_table, ao);

    // proj: M=100352, N=512, K=512 -> 392*2 = 784 blocks (%8==0)
    gemm256<float><<<784, 512, 131072, stream>>>(
        ao, pw, proj_b, (float*)d_out, MROWS, CDIM, CDIM, 2, 98);
}

// Round 3
// 754.234 us; speedup vs baseline: 1.6745x; 1.0264x over previous
//
#include <hip/hip_runtime.h>
#include <hip/hip_bf16.h>

// ---------------------------------------------------------------------------
// WindowAttention (Swin-style), MI355X / gfx950
//   x:(2048,49,512) f32 -> qkv GEMM (256^2 2-barrier deep-pipe bf16 MFMA)
//   -> attention (MFMA) -> proj GEMM -> out f32
// ---------------------------------------------------------------------------

typedef __bf16  bf16x8 __attribute__((ext_vector_type(8)));
typedef float   f32x4  __attribute__((ext_vector_type(4)));

#define B_TOT   2048
#define NTOK    49
#define CDIM    512
#define NHEAD   16
#define HDIM    32
#define MROWS   (B_TOT * NTOK)      // 100352
#define QKVN    (3 * CDIM)          // 1536

// ---- async global->LDS ------------------------------------------------------
__device__ __forceinline__ void load_lds16(const void* gptr, void* lptr) {
    __builtin_amdgcn_global_load_lds(
        (const __attribute__((address_space(1))) unsigned int*)gptr,
        (__attribute__((address_space(3))) unsigned int*)lptr,
        16, 0, 0);
}
__device__ __forceinline__ void load_lds4(const void* gptr, void* lptr) {
    __builtin_amdgcn_global_load_lds(
        (const __attribute__((address_space(1))) unsigned int*)gptr,
        (__attribute__((address_space(3))) unsigned int*)lptr,
        4, 0, 0);
}

// ---- fp32 -> bf16 convert (vectorized) -------------------------------------
__global__ void cvt_f32_bf16(const float* __restrict__ in,
                             __hip_bfloat16* __restrict__ out, int n4) {
    int idx = blockIdx.x * blockDim.x + threadIdx.x;
    int stride = gridDim.x * blockDim.x;
    for (int i = idx; i < n4; i += stride) {
        float4 f = ((const float4*)in)[i];
        union { __hip_bfloat16 h[4]; ushort4 u; } c;
        c.h[0] = __float2bfloat16(f.x);
        c.h[1] = __float2bfloat16(f.y);
        c.h[2] = __float2bfloat16(f.z);
        c.h[3] = __float2bfloat16(f.w);
        ((ushort4*)out)[i] = c.u;
    }
}

// ---------------------------------------------------------------------------
// 256x256 deep-pipelined GEMM, C = A @ B^T + bias.
// A (M,K) bf16 rm, B (N,K) bf16 rm. M%256==0, N%256==0, K = 512 (NT=8).
// 8 waves (2M x 4N), per-wave 128x64 output. K-tile = 64.
// LDS per matrix: 2 slabs (t&1) x 2 halves x [128 rows][128 bytes] = 64KB.
// Swizzle: byte_col ^= ((row&7)<<4)  => wave64 ds_read_b128 covers all 32
// banks uniformly (2-way = free). Staging writes LINEAR LDS; the global
// SOURCE is pre-inverse-swizzled (per-thread constant offset).
// Pipeline per K-tile t (2 barriers only):
//   reads: B all 8 frags + A clusters (24 x b128 total, held in regs)
//   MFMA c1..c3 (16 each) interleaved with A reads
//   read A c4 frags; lgkmcnt(0); BARRIER   <- slab t&1 fully dead
//   stage K-tile t+2 into slab t&1 (8 global_load_lds, WAR-safe)
//   MFMA c4 (16)
//   vmcnt(8)  <- t+1's 8 loads retired; t+2's 8 stay in flight (never 0)
//   BARRIER   <- publishes t+1 to all waves
// ---------------------------------------------------------------------------
#define BARR    asm volatile("s_barrier" ::: "memory")
#define WAITV(N) asm volatile("s_waitcnt vmcnt(" #N ")" ::: "memory")
#define MFMA16(av, bv, cv) __builtin_amdgcn_mfma_f32_16x16x32_bf16(av, bv, cv, 0, 0, 0)

template <typename OutT>
__global__ __launch_bounds__(512, 2) void gemm256(
    const __hip_bfloat16* __restrict__ A,
    const __hip_bfloat16* __restrict__ B,
    const float* __restrict__ bias,
    OutT* __restrict__ C,
    int M, int N, int K, int nbx, int cpx)
{
    extern __shared__ __align__(16) char smem[];
    char* sA = smem;
    char* sB = smem + 65536;

    const int NT = K >> 6;           // 8

    const int tid  = threadIdx.x;
    const int lane = tid & 63;
    const int wave = tid >> 6;
    const int wm   = wave >> 2;      // 0..1  (M half)
    const int wn   = wave & 3;       // 0..3  (64-col N strip)
    const int l16  = lane & 15;
    const int quad = lane >> 4;

    // bijective XCD swizzle (gridDim %8==0)
    const int id = blockIdx.x;
    const int sw = (id & 7) * cpx + (id >> 3);
    const int mb = sw / nbx;
    const int nb = sw - mb * nbx;
    const int m0 = mb << 8;
    const int n0 = nb << 8;

    // ---- staging constants (inverse-swizzled global source) ----------------
    // LDS linear byte L = (j*512+tid)*16 within a 16KB half-tile:
    //   row r = j*64 + (tid>>3), swz col = (tid&7)*16
    //   orig col = swz ^ ((r&7)<<4)  -> element offset scg (per-thread const)
    const int srow = tid >> 3;                                  // 0..63
    const int scg  = ((tid & 7) << 3) ^ ((srow & 7) << 3);      // elems, 0..63
    const __hip_bfloat16* Asrc = A + (size_t)(m0 + srow) * K + scg;
    const __hip_bfloat16* Bsrc = B + (size_t)(n0 + srow) * K + scg;
    char* dAl = sA + tid * 16;
    char* dBl = sB + tid * 16;

#define STG_A(t2, h) \
    { load_lds16(Asrc + (size_t)(h) * 128 * K + (t2) * 64,            \
                 dAl + ((t2) & 1) * 32768 + (h) * 16384);             \
      load_lds16(Asrc + ((size_t)(h) * 128 + 64) * K + (t2) * 64,     \
                 dAl + ((t2) & 1) * 32768 + (h) * 16384 + 8192); }
#define STG_B(t2, h) \
    { load_lds16(Bsrc + (size_t)(h) * 128 * K + (t2) * 64,            \
                 dBl + ((t2) & 1) * 32768 + (h) * 16384);             \
      load_lds16(Bsrc + ((size_t)(h) * 128 + 64) * K + (t2) * 64,     \
                 dBl + ((t2) & 1) * 32768 + (h) * 16384 + 8192); }

    // prologue: tiles 0 and 1 (8 instrs each); keep tile1 in flight
    STG_A(0, 0); STG_A(0, 1); STG_B(0, 0); STG_B(0, 1);
    STG_A(1, 0); STG_A(1, 1); STG_B(1, 0); STG_B(1, 1);
    WAITV(8);
    BARR;

    // fragment read columns (swizzled): ks=0 -> c0, ks=1 -> c0^64
    const int c0 = (quad * 16) ^ ((l16 & 7) << 4);
    const int c1 = c0 ^ 64;

    f32x4 acc[8][4] = {};

#define CLUSTER(mfa, mfb)                                                  \
    {                                                                      \
        bf16x8 xk0 = *(const bf16x8*)(pA + (mfa) * 2048 + c0);             \
        bf16x8 xk1 = *(const bf16x8*)(pA + (mfa) * 2048 + c1);             \
        bf16x8 yk0 = *(const bf16x8*)(pA + (mfb) * 2048 + c0);             \
        bf16x8 yk1 = *(const bf16x8*)(pA + (mfb) * 2048 + c1);             \
        __builtin_amdgcn_s_setprio(1);                                     \
        _Pragma("unroll")                                                  \
        for (int nf = 0; nf < 4; ++nf) {                                   \
            acc[mfa][nf] = MFMA16(xk0, Bf0[nf], acc[mfa][nf]);             \
            acc[mfa][nf] = MFMA16(xk1, Bf1[nf], acc[mfa][nf]);             \
            acc[mfb][nf] = MFMA16(yk0, Bf0[nf], acc[mfb][nf]);             \
            acc[mfb][nf] = MFMA16(yk1, Bf1[nf], acc[mfb][nf]);             \
        }                                                                  \
        __builtin_amdgcn_s_setprio(0);                                     \
    }

#pragma unroll 2
    for (int t = 0; t < NT; ++t) {
        const int sl = (t & 1) * 32768;
        const char* pA = sA + sl + wm * 16384 + l16 * 128;
        const char* pB = sB + sl + (wn >> 1) * 16384 + ((wn & 1) * 64 + l16) * 128;

        // B: all 8 frags for this K-tile, held across clusters
        bf16x8 Bf0[4], Bf1[4];
#pragma unroll
        for (int nf = 0; nf < 4; ++nf) {
            Bf0[nf] = *(const bf16x8*)(pB + nf * 2048 + c0);
            Bf1[nf] = *(const bf16x8*)(pB + nf * 2048 + c1);
        }

        CLUSTER(0, 1);
        CLUSTER(2, 3);
        CLUSTER(4, 5);

        // cluster 4 reads must complete BEFORE the barrier (slab reuse)
        bf16x8 a6k0 = *(const bf16x8*)(pA + 6 * 2048 + c0);
        bf16x8 a6k1 = *(const bf16x8*)(pA + 6 * 2048 + c1);
        bf16x8 a7k0 = *(const bf16x8*)(pA + 7 * 2048 + c0);
        bf16x8 a7k1 = *(const bf16x8*)(pA + 7 * 2048 + c1);
        asm volatile("s_waitcnt lgkmcnt(0)" ::: "memory");
        BARR;                                  // slab t&1 dead -> writable

        if (t + 2 < NT) { STG_A(t + 2, 0); STG_A(t + 2, 1);
                          STG_B(t + 2, 0); STG_B(t + 2, 1); }

        __builtin_amdgcn_s_setprio(1);
#pragma unroll
        for (int nf = 0; nf < 4; ++nf) {
            acc[6][nf] = MFMA16(a6k0, Bf0[nf], acc[6][nf]);
            acc[6][nf] = MFMA16(a6k1, Bf1[nf], acc[6][nf]);
            acc[7][nf] = MFMA16(a7k0, Bf0[nf], acc[7][nf]);
            acc[7][nf] = MFMA16(a7k1, Bf1[nf], acc[7][nf]);
        }
        __builtin_amdgcn_s_setprio(0);

        if (t + 2 < NT) { WAITV(8); }          // t+1 retired, t+2 in flight
        else if (t + 1 < NT) { WAITV(0); }     // tail: last tile must land
        BARR;
    }
#undef CLUSTER
#undef STG_A
#undef STG_B

    // epilogue: D row = quad*4+r, col = l16 (verified layout)
#pragma unroll
    for (int i = 0; i < 8; ++i) {
#pragma unroll
        for (int jj = 0; jj < 4; ++jj) {
            const int col = n0 + wn * 64 + jj * 16 + l16;
            const float bv = bias[col];
#pragma unroll
            for (int rr = 0; rr < 4; ++rr) {
                const int row = m0 + wm * 128 + i * 16 + quad * 4 + rr;
                const float val = acc[i][jj][rr] + bv;
                if constexpr (sizeof(OutT) == 2)
                    C[(size_t)row * N + col] = __float2bfloat16(val);
                else
                    C[(size_t)row * N + col] = val;
            }
        }
    }
}

// ---------------------------------------------------------------------------
// MFMA window attention. 1 block = 4 waves = heads hq*4..hq*4+3 of batch b.
// (unchanged)
// ---------------------------------------------------------------------------
#define QS_OFF   0
#define KS_OFF   12544
#define VS_OFF   25088
#define BIAS_OFF 41472
#define MASK_OFF 42824
#define SMEM_BYTES 52432

__global__ __launch_bounds__(256) void attn_mfma(
    const __hip_bfloat16* __restrict__ qkv,
    const float* __restrict__ mask,        // (64, 49, 49)
    const float* __restrict__ bias_table,  // (169, 16)
    __hip_bfloat16* __restrict__ out)
{
    __shared__ __align__(16) char smem[SMEM_BYTES];

    const int tid  = threadIdx.x;
    const int lane = tid & 63;
    const int w    = tid >> 6;
    const int l16  = lane & 15;
    const int quad = lane >> 4;
    const int b    = blockIdx.x >> 2;
    const int hq   = blockIdx.x & 3;

    {
        const long rowbase = (long)b * NTOK * QKVN;
        for (int e = tid; e < 2352; e += 256) {
            const int m   = e / 784;
            const int rr  = e - m * 784;
            const int tok = rr >> 4, seg = rr & 15;
            const int segl = seg ^ (tok & 7);
            const __hip_bfloat16* src =
                qkv + rowbase + (long)tok * QKVN + m * 512 + hq * 128 + segl * 8;
            load_lds16(src, smem + e * 16);
        }
        for (int e = tid; e < 960; e += 256)
            ((unsigned int*)(smem + VS_OFF + 49 * 256))[e] = 0u;
        const float* msrc = mask + (long)(b & 63) * (NTOK * NTOK);
        for (int e = tid; e < NTOK * NTOK; e += 256)
            load_lds4(msrc + e, smem + MASK_OFF + e * 4);
        __hip_bfloat16* sb = (__hip_bfloat16*)(smem + BIAS_OFF);
        for (int e = tid; e < 676; e += 256) {
            const int w2 = e / 169, rel = e - w2 * 169;
            sb[e] = __float2bfloat16(bias_table[rel * NHEAD + hq * 4 + w2]);
        }
    }
    __syncthreads();

    const int fro = (w * 64 + quad * 16) ^ ((l16 & 7) << 4);
    bf16x8 af[4], bf[4];
#pragma unroll
    for (int t = 0; t < 4; ++t) {
        const int tok = t * 16 + l16;
        af[t] = *(const bf16x8*)(smem + KS_OFF + tok * 256 + fro);
        bf[t] = *(const bf16x8*)(smem + QS_OFF + tok * 256 + fro);
    }
    f32x4 acc[4][4] = {};
#pragma unroll
    for (int i = 0; i < 4; ++i)
#pragma unroll
        for (int j = 0; j < 4; ++j)
            acc[i][j] = __builtin_amdgcn_mfma_f32_16x16x32_bf16(
                af[i], bf[j], acc[i][j], 0, 0, 0);
    __syncthreads();

    const float scale = 0.17677669529663687f;
    const float* smf = (const float*)(smem + MASK_OFF);
    const __hip_bfloat16* sb = (const __hip_bfloat16*)(smem + BIAS_OFF);
    const int quad4 = quad * 4;

    int kp[4][4];
#pragma unroll
    for (int i = 0; i < 4; ++i)
#pragma unroll
        for (int r = 0; r < 4; ++r) {
            const int k  = i * 16 + quad4 + r;
            const int rj = k / 7, cj = k - rj * 7;
            kp[i][r] = (6 - rj) * 13 + (6 - cj);
        }

    char* pbase = smem + w * 6272;
#pragma unroll
    for (int j = 0; j < 4; ++j) {
        const int q   = j * 16 + l16;
        const bool qok = q < NTOK;
        const int ri  = q / 7, ci = q - ri * 7;
        const int qp  = ri * 13 + ci;
        const int mrow = q * NTOK;
        float mx = -1e30f;
#pragma unroll
        for (int i = 0; i < 4; ++i)
#pragma unroll
            for (int r = 0; r < 4; ++r) {
                const int k = i * 16 + quad4 + r;
                float v;
                if (qok && k < NTOK) {
                    v = fmaf(acc[i][j][r], scale,
                             __bfloat162float(sb[w * 169 + qp + kp[i][r]]) + smf[mrow + k]);
                } else {
                    v = -1e30f;
                }
                acc[i][j][r] = v;
                mx = fmaxf(mx, v);
            }
        mx = fmaxf(mx, __shfl_xor(mx, 16));
        mx = fmaxf(mx, __shfl_xor(mx, 32));
        float s = 0.f;
#pragma unroll
        for (int i = 0; i < 4; ++i)
#pragma unroll
            for (int r = 0; r < 4; ++r) {
                const float ev = __expf(acc[i][j][r] - mx);
                acc[i][j][r] = ev;
                s += ev;
            }
        s += __shfl_xor(s, 16);
        s += __shfl_xor(s, 32);
        const float inv = 1.0f / s;
        if (qok) {
            char* prow = pbase + q * 128;
            const int xr = (q & 7) << 4;
#pragma unroll
            for (int i = 0; i < 4; ++i) {
                union { __hip_bfloat16 h[4]; uint2 u; } pk;
#pragma unroll
                for (int r = 0; r < 4; ++r)
                    pk.h[r] = __float2bfloat16(acc[i][j][r] * inv);
                *(uint2*)(prow + ((i * 32 + quad * 8) ^ xr)) = pk.u;
            }
        }
    }
    __syncthreads();

    bf16x8 pa[4][2];
#pragma unroll
    for (int mt = 0; mt < 4; ++mt) {
        const int q  = mt * 16 + l16;
        const int xr = (q & 7) << 4;
#pragma unroll
        for (int ks = 0; ks < 2; ++ks)
            pa[mt][ks] = *(const bf16x8*)(pbase + q * 128 + ((ks * 64 + quad * 16) ^ xr));
    }
    bf16x8 vb[2][2];
#pragma unroll
    for (int dt = 0; dt < 2; ++dt)
#pragma unroll
        for (int ks = 0; ks < 2; ++ks)
#pragma unroll
            for (int e = 0; e < 8; ++e) {
                const int key = ks * 32 + quad * 8 + e;
                const int dby = (w * 32 + dt * 16 + l16) * 2;
                vb[dt][ks][e] = *(const __bf16*)(smem + VS_OFF + key * 256 + (dby ^ (e << 4)));
            }
    f32x4 o[4][2] = {};
#pragma unroll
    for (int mt = 0; mt < 4; ++mt)
#pragma unroll
        for (int dt = 0; dt < 2; ++dt)
#pragma unroll
            for (int ks = 0; ks < 2; ++ks)
                o[mt][dt] = __builtin_amdgcn_mfma_f32_16x16x32_bf16(
                    pa[mt][ks], vb[dt][ks], o[mt][dt], 0, 0, 0);

    const long obase = (long)b * NTOK * CDIM + hq * 128 + w * 32;
#pragma unroll
    for (int mt = 0; mt < 4; ++mt)
#pragma unroll
        for (int r = 0; r < 4; ++r) {
            const int q = mt * 16 + quad4 + r;
            if (q < NTOK) {
                const long rb = obase + (long)q * CDIM;
#pragma unroll
                for (int dt = 0; dt < 2; ++dt)
                    out[rb + dt * 16 + l16] = __float2bfloat16(o[mt][dt][r]);
            }
        }
}

// ---------------------------------------------------------------------------
extern "C" void kernel_launch(void* const* d_in, const int* in_sizes, int n_in,
                              void* d_out, int out_size, void* d_ws, size_t ws_size,
                              hipStream_t stream) {
    const float* x          = (const float*)d_in[0];
    const float* mask       = (const float*)d_in[1];
    const float* qkv_w      = (const float*)d_in[2];
    const float* qkv_b      = (const float*)d_in[3];
    const float* proj_w     = (const float*)d_in[4];
    const float* proj_b     = (const float*)d_in[5];
    const float* bias_table = (const float*)d_in[6];

    char* ws = (char*)d_ws;
    __hip_bfloat16* xb   = (__hip_bfloat16*)(ws);
    __hip_bfloat16* qw   = (__hip_bfloat16*)(ws + 102760448);
    __hip_bfloat16* pw   = (__hip_bfloat16*)(ws + 104333312);
    __hip_bfloat16* qkvb = (__hip_bfloat16*)(ws + 104857600);
    __hip_bfloat16* ao   = xb;  // attn out reuses x_bf16 (GEMM1 done by then)

    static int attr_done = 0;
    if (!attr_done) {
        hipFuncSetAttribute(
            reinterpret_cast<const void*>(&gemm256<__hip_bfloat16>),
            hipFuncAttributeMaxDynamicSharedMemorySize, 131072);
        hipFuncSetAttribute(
            reinterpret_cast<const void*>(&gemm256<float>),
            hipFuncAttributeMaxDynamicSharedMemorySize, 131072);
        attr_done = 1;
    }

    cvt_f32_bf16<<<32768, 256, 0, stream>>>(x, xb, (MROWS * CDIM) / 4);
    cvt_f32_bf16<<<768,   256, 0, stream>>>(qkv_w, qw, (QKVN * CDIM) / 4);
    cvt_f32_bf16<<<256,   256, 0, stream>>>(proj_w, pw, (CDIM * CDIM) / 4);

    // qkv: M=100352, N=1536, K=512 -> 392*6 = 2352 blocks (%8==0)
    gemm256<__hip_bfloat16><<<2352, 512, 131072, stream>>>(
        xb, qw, qkv_b, qkvb, MROWS, QKVN, CDIM, 6, 294);

    attn_mfma<<<B_TOT * 4, 256, 0, stream>>>(qkvb, mask, bias_table, ao);

    // proj: M=100352, N=512, K=512 -> 392*2 = 784 blocks (%8==0)
    gemm256<float><<<784, 512, 131072, stream>>>(
        ao, pw, proj_b, (float*)d_out, MROWS, CDIM, CDIM, 2, 98);
}

// Round 4
// 713.776 us; speedup vs baseline: 1.7694x; 1.0567x over previous
//
#include <hip/hip_runtime.h>
#include <hip/hip_bf16.h>

// ---------------------------------------------------------------------------
// WindowAttention (Swin-style), MI355X / gfx950
//   x:(2048,49,512) f32 -> qkv GEMM (256^2 8-phase bf16 MFMA, m201 schedule)
//   -> attention (MFMA) -> proj GEMM -> out f32
// ---------------------------------------------------------------------------

typedef __bf16  bf16x8 __attribute__((ext_vector_type(8)));
typedef float   f32x4  __attribute__((ext_vector_type(4)));

#define B_TOT   2048
#define NTOK    49
#define CDIM    512
#define NHEAD   16
#define HDIM    32
#define MROWS   (B_TOT * NTOK)      // 100352
#define QKVN    (3 * CDIM)          // 1536

// ---- async global->LDS ------------------------------------------------------
__device__ __forceinline__ void load_lds16(const void* gptr, void* lptr) {
    __builtin_amdgcn_global_load_lds(
        (const __attribute__((address_space(1))) unsigned int*)gptr,
        (__attribute__((address_space(3))) unsigned int*)lptr,
        16, 0, 0);
}
__device__ __forceinline__ void load_lds4(const void* gptr, void* lptr) {
    __builtin_amdgcn_global_load_lds(
        (const __attribute__((address_space(1))) unsigned int*)gptr,
        (__attribute__((address_space(3))) unsigned int*)lptr,
        4, 0, 0);
}

// ---- fp32 -> bf16 convert (vectorized) -------------------------------------
__global__ void cvt_f32_bf16(const float* __restrict__ in,
                             __hip_bfloat16* __restrict__ out, int n4) {
    int idx = blockIdx.x * blockDim.x + threadIdx.x;
    int stride = gridDim.x * blockDim.x;
    for (int i = idx; i < n4; i += stride) {
        float4 f = ((const float4*)in)[i];
        union { __hip_bfloat16 h[4]; ushort4 u; } c;
        c.h[0] = __float2bfloat16(f.x);
        c.h[1] = __float2bfloat16(f.y);
        c.h[2] = __float2bfloat16(f.z);
        c.h[3] = __float2bfloat16(f.w);
        ((ushort4*)out)[i] = c.u;
    }
}

// ---------------------------------------------------------------------------
// 256x256 8-phase GEMM (m201 schedule), C = A @ B^T + bias.
// A (M,K) bf16 rm, B (N,K) bf16 rm. M%256==0, N%256==0, K==512 (NT=8).
// 8 waves (2M x 4N), per-wave 128x64 output. K-tile = 64, 2 tiles/iter.
// LDS per matrix: 2 slabs x 2 halves x [128 rows][128 B] = 64KB.
// Swizzle byte ^= ((row&7)<<4): zero bank conflicts (verified R3). Staging
// writes LINEAR LDS; global SOURCE pre-inverse-swizzled.
// Per phase: {ds-read subtile ; stage ONE half-tile (2 gload_lds) ; barrier ;
//   lgkmcnt(0) ; setprio(1) 16 MFMA setprio(0) ; [vmcnt(4) at ph4/ph8] ;
//   barrier}.  Quadrants per tile: (m0,n0),(m0,n1),(m1,n0),(m1,n1);
//   A-half read once (held 2 phases), B-halves held 3 phases.
// Stage order/iter: A0(u)@1 A1(u)@2 B0(t+2)@3 B1(t+2)@4 A0(t+2)@5 A1(t+2)@6
//   B0(t+3)@7 B1(t+3)@8   (u = t+1)
// Ledger: vmcnt(4)@ph4 retires exactly tile t+1; @ph8 exactly tile t+2;
//   2 half-tiles (4 loads) ALWAYS in flight. WAR: every stage target is
//   >=1 phase past its last all-waves read (A halves die after quadrant
//   (m1,*) phase; B halves after (*,n1) phase).
// ---------------------------------------------------------------------------
#define BARR    asm volatile("s_barrier" ::: "memory")
#define WAITV(N) asm volatile("s_waitcnt vmcnt(" #N ")" ::: "memory")
#define LGKM0   asm volatile("s_waitcnt lgkmcnt(0)" ::: "memory")
#define MFMA16(av, bv, cv) __builtin_amdgcn_mfma_f32_16x16x32_bf16(av, bv, cv, 0, 0, 0)

template <typename OutT>
__global__ __launch_bounds__(512, 2) void gemm256(
    const __hip_bfloat16* __restrict__ A,
    const __hip_bfloat16* __restrict__ B,
    const float* __restrict__ bias,
    OutT* __restrict__ C,
    int M, int N, int K, int nbx, int cpx)
{
    extern __shared__ __align__(16) char smem[];
    char* sA = smem;
    char* sB = smem + 65536;

    const int tid  = threadIdx.x;
    const int lane = tid & 63;
    const int wave = tid >> 6;
    const int wm   = wave >> 2;      // 0..1  (M half)
    const int wn   = wave & 3;       // 0..3  (64-col N strip)
    const int l16  = lane & 15;
    const int quad = lane >> 4;

    // bijective XCD swizzle (gridDim %8==0)
    const int id = blockIdx.x;
    const int sw = (id & 7) * cpx + (id >> 3);
    const int mb = sw / nbx;
    const int nb = sw - mb * nbx;
    const int m0 = mb << 8;
    const int n0 = nb << 8;

    // ---- staging constants (inverse-swizzled global source) ----------------
    const int srow = tid >> 3;                                  // 0..63
    const int scg  = ((tid & 7) << 3) ^ ((srow & 7) << 3);      // elems
    const __hip_bfloat16* Asrc = A + (size_t)(m0 + srow) * K + scg;
    const __hip_bfloat16* Bsrc = B + (size_t)(n0 + srow) * K + scg;
    char* dAl = sA + tid * 16;
    char* dBl = sB + tid * 16;

#define STG_A(t2, h) \
    { load_lds16(Asrc + (size_t)(h) * 128 * K + (t2) * 64,            \
                 dAl + ((t2) & 1) * 32768 + (h) * 16384);             \
      load_lds16(Asrc + ((size_t)(h) * 128 + 64) * K + (t2) * 64,     \
                 dAl + ((t2) & 1) * 32768 + (h) * 16384 + 8192); }
#define STG_B(t2, h) \
    { load_lds16(Bsrc + (size_t)(h) * 128 * K + (t2) * 64,            \
                 dBl + ((t2) & 1) * 32768 + (h) * 16384);             \
      load_lds16(Bsrc + ((size_t)(h) * 128 + 64) * K + (t2) * 64,     \
                 dBl + ((t2) & 1) * 32768 + (h) * 16384 + 8192); }

    // prologue: [A0(0) A1(0) B0(0) B1(0) B0(1) B1(1)] ; retire tile0, keep 4
    STG_A(0, 0); STG_A(0, 1); STG_B(0, 0); STG_B(0, 1);
    STG_B(1, 0); STG_B(1, 1);
    WAITV(4);
    BARR;

    // loop-invariant read bases (tile t even -> slab0, t+1 -> slab1)
    const char* pA0 = sA + wm * 16384 + l16 * 128;
    const char* pA1 = pA0 + 32768;
    const char* pB0 = sB + (wn >> 1) * 16384 + (wn & 1) * 8192 + l16 * 128;
    const char* pB1 = pB0 + 32768;
    const int c0 = (quad * 16) ^ ((l16 & 7) << 4);
    const int c1 = c0 ^ 64;

    bf16x8 ar[8], b0r[4], b1r[4];
    f32x4 acc[8][4] = {};

#define PH_READS_A(pA, mh)                                                  \
    _Pragma("unroll") for (int i = 0; i < 4; ++i) {                         \
        ar[2 * i]     = *(const bf16x8*)((pA) + (mh) * 8192 + i * 2048 + c0); \
        ar[2 * i + 1] = *(const bf16x8*)((pA) + (mh) * 8192 + i * 2048 + c1); \
    }
#define PH_READS_B(pB, nh, br)                                              \
    _Pragma("unroll") for (int j = 0; j < 2; ++j) {                         \
        br[2 * j]     = *(const bf16x8*)((pB) + (nh) * 4096 + j * 2048 + c0); \
        br[2 * j + 1] = *(const bf16x8*)((pB) + (nh) * 4096 + j * 2048 + c1); \
    }
#define PH_MFMA(mh, nh, br)                                                 \
    __builtin_amdgcn_s_setprio(1);                                          \
    _Pragma("unroll") for (int i = 0; i < 4; ++i)                           \
    _Pragma("unroll") for (int j = 0; j < 2; ++j) {                         \
        acc[(mh) * 4 + i][(nh) * 2 + j] = MFMA16(                           \
            ar[2 * i], br[2 * j], acc[(mh) * 4 + i][(nh) * 2 + j]);         \
        acc[(mh) * 4 + i][(nh) * 2 + j] = MFMA16(                           \
            ar[2 * i + 1], br[2 * j + 1], acc[(mh) * 4 + i][(nh) * 2 + j]); \
    }                                                                       \
    __builtin_amdgcn_s_setprio(0);

#pragma unroll
    for (int it = 0; it < 4; ++it) {
        const int t = 2 * it, u = t + 1;
        const bool more = (it < 3);

        // ---- tile t (slab0) ------------------------------------------------
        // ph1: (m0,n0)
        PH_READS_A(pA0, 0); PH_READS_B(pB0, 0, b0r);
        STG_A(u, 0);
        BARR; LGKM0; PH_MFMA(0, 0, b0r); BARR;
        // ph2: (m0,n1)
        PH_READS_B(pB0, 1, b1r);
        STG_A(u, 1);
        BARR; LGKM0; PH_MFMA(0, 1, b1r); BARR;
        // ph3: (m1,n0)
        PH_READS_A(pA0, 1);
        if (more) STG_B(t + 2, 0);
        BARR; LGKM0; PH_MFMA(1, 0, b0r); BARR;
        // ph4: (m1,n1)
        if (more) STG_B(t + 2, 1);
        BARR; PH_MFMA(1, 1, b1r);
        if (more) { WAITV(4); } else { WAITV(0); }   // tile t+1 landed
        BARR;

        // ---- tile u = t+1 (slab1) ------------------------------------------
        // ph5: (m0,n0)
        PH_READS_A(pA1, 0); PH_READS_B(pB1, 0, b0r);
        if (more) STG_A(t + 2, 0);
        BARR; LGKM0; PH_MFMA(0, 0, b0r); BARR;
        // ph6: (m0,n1)
        PH_READS_B(pB1, 1, b1r);
        if (more) STG_A(t + 2, 1);
        BARR; LGKM0; PH_MFMA(0, 1, b1r); BARR;
        // ph7: (m1,n0)
        PH_READS_A(pA1, 1);
        if (more) STG_B(t + 3, 0);
        BARR; LGKM0; PH_MFMA(1, 0, b0r); BARR;
        // ph8: (m1,n1)
        if (more) STG_B(t + 3, 1);
        BARR; PH_MFMA(1, 1, b1r);
        if (more) { WAITV(4); }                      // tile t+2 landed
        BARR;
    }
#undef PH_READS_A
#undef PH_READS_B
#undef PH_MFMA
#undef STG_A
#undef STG_B

    // epilogue: D row = quad*4+r, col = l16 (verified layout)
#pragma unroll
    for (int i = 0; i < 8; ++i) {
#pragma unroll
        for (int jj = 0; jj < 4; ++jj) {
            const int col = n0 + wn * 64 + jj * 16 + l16;
            const float bv = bias[col];
#pragma unroll
            for (int rr = 0; rr < 4; ++rr) {
                const int row = m0 + wm * 128 + i * 16 + quad * 4 + rr;
                const float val = acc[i][jj][rr] + bv;
                if constexpr (sizeof(OutT) == 2)
                    C[(size_t)row * N + col] = __float2bfloat16(val);
                else
                    C[(size_t)row * N + col] = val;
            }
        }
    }
}

// ---------------------------------------------------------------------------
// MFMA window attention. 1 block = 4 waves = heads hq*4..hq*4+3 of batch b.
// (unchanged)
// ---------------------------------------------------------------------------
#define QS_OFF   0
#define KS_OFF   12544
#define VS_OFF   25088
#define BIAS_OFF 41472
#define MASK_OFF 42824
#define SMEM_BYTES 52432

__global__ __launch_bounds__(256) void attn_mfma(
    const __hip_bfloat16* __restrict__ qkv,
    const float* __restrict__ mask,        // (64, 49, 49)
    const float* __restrict__ bias_table,  // (169, 16)
    __hip_bfloat16* __restrict__ out)
{
    __shared__ __align__(16) char smem[SMEM_BYTES];

    const int tid  = threadIdx.x;
    const int lane = tid & 63;
    const int w    = tid >> 6;
    const int l16  = lane & 15;
    const int quad = lane >> 4;
    const int b    = blockIdx.x >> 2;
    const int hq   = blockIdx.x & 3;

    {
        const long rowbase = (long)b * NTOK * QKVN;
        for (int e = tid; e < 2352; e += 256) {
            const int m   = e / 784;
            const int rr  = e - m * 784;
            const int tok = rr >> 4, seg = rr & 15;
            const int segl = seg ^ (tok & 7);
            const __hip_bfloat16* src =
                qkv + rowbase + (long)tok * QKVN + m * 512 + hq * 128 + segl * 8;
            load_lds16(src, smem + e * 16);
        }
        for (int e = tid; e < 960; e += 256)
            ((unsigned int*)(smem + VS_OFF + 49 * 256))[e] = 0u;
        const float* msrc = mask + (long)(b & 63) * (NTOK * NTOK);
        for (int e = tid; e < NTOK * NTOK; e += 256)
            load_lds4(msrc + e, smem + MASK_OFF + e * 4);
        __hip_bfloat16* sb = (__hip_bfloat16*)(smem + BIAS_OFF);
        for (int e = tid; e < 676; e += 256) {
            const int w2 = e / 169, rel = e - w2 * 169;
            sb[e] = __float2bfloat16(bias_table[rel * NHEAD + hq * 4 + w2]);
        }
    }
    __syncthreads();

    const int fro = (w * 64 + quad * 16) ^ ((l16 & 7) << 4);
    bf16x8 af[4], bf[4];
#pragma unroll
    for (int t = 0; t < 4; ++t) {
        const int tok = t * 16 + l16;
        af[t] = *(const bf16x8*)(smem + KS_OFF + tok * 256 + fro);
        bf[t] = *(const bf16x8*)(smem + QS_OFF + tok * 256 + fro);
    }
    f32x4 acc[4][4] = {};
#pragma unroll
    for (int i = 0; i < 4; ++i)
#pragma unroll
        for (int j = 0; j < 4; ++j)
            acc[i][j] = __builtin_amdgcn_mfma_f32_16x16x32_bf16(
                af[i], bf[j], acc[i][j], 0, 0, 0);
    __syncthreads();

    const float scale = 0.17677669529663687f;
    const float* smf = (const float*)(smem + MASK_OFF);
    const __hip_bfloat16* sb = (const __hip_bfloat16*)(smem + BIAS_OFF);
    const int quad4 = quad * 4;

    int kp[4][4];
#pragma unroll
    for (int i = 0; i < 4; ++i)
#pragma unroll
        for (int r = 0; r < 4; ++r) {
            const int k  = i * 16 + quad4 + r;
            const int rj = k / 7, cj = k - rj * 7;
            kp[i][r] = (6 - rj) * 13 + (6 - cj);
        }

    char* pbase = smem + w * 6272;
#pragma unroll
    for (int j = 0; j < 4; ++j) {
        const int q   = j * 16 + l16;
        const bool qok = q < NTOK;
        const int ri  = q / 7, ci = q - ri * 7;
        const int qp  = ri * 13 + ci;
        const int mrow = q * NTOK;
        float mx = -1e30f;
#pragma unroll
        for (int i = 0; i < 4; ++i)
#pragma unroll
            for (int r = 0; r < 4; ++r) {
                const int k = i * 16 + quad4 + r;
                float v;
                if (qok && k < NTOK) {
                    v = fmaf(acc[i][j][r], scale,
                             __bfloat162float(sb[w * 169 + qp + kp[i][r]]) + smf[mrow + k]);
                } else {
                    v = -1e30f;
                }
                acc[i][j][r] = v;
                mx = fmaxf(mx, v);
            }
        mx = fmaxf(mx, __shfl_xor(mx, 16));
        mx = fmaxf(mx, __shfl_xor(mx, 32));
        float s = 0.f;
#pragma unroll
        for (int i = 0; i < 4; ++i)
#pragma unroll
            for (int r = 0; r < 4; ++r) {
                const float ev = __expf(acc[i][j][r] - mx);
                acc[i][j][r] = ev;
                s += ev;
            }
        s += __shfl_xor(s, 16);
        s += __shfl_xor(s, 32);
        const float inv = 1.0f / s;
        if (qok) {
            char* prow = pbase + q * 128;
            const int xr = (q & 7) << 4;
#pragma unroll
            for (int i = 0; i < 4; ++i) {
                union { __hip_bfloat16 h[4]; uint2 u; } pk;
#pragma unroll
                for (int r = 0; r < 4; ++r)
                    pk.h[r] = __float2bfloat16(acc[i][j][r] * inv);
                *(uint2*)(prow + ((i * 32 + quad * 8) ^ xr)) = pk.u;
            }
        }
    }
    __syncthreads();

    bf16x8 pa[4][2];
#pragma unroll
    for (int mt = 0; mt < 4; ++mt) {
        const int q  = mt * 16 + l16;
        const int xr = (q & 7) << 4;
#pragma unroll
        for (int ks = 0; ks < 2; ++ks)
            pa[mt][ks] = *(const bf16x8*)(pbase + q * 128 + ((ks * 64 + quad * 16) ^ xr));
    }
    bf16x8 vb[2][2];
#pragma unroll
    for (int dt = 0; dt < 2; ++dt)
#pragma unroll
        for (int ks = 0; ks < 2; ++ks)
#pragma unroll
            for (int e = 0; e < 8; ++e) {
                const int key = ks * 32 + quad * 8 + e;
                const int dby = (w * 32 + dt * 16 + l16) * 2;
                vb[dt][ks][e] = *(const __bf16*)(smem + VS_OFF + key * 256 + (dby ^ (e << 4)));
            }
    f32x4 o[4][2] = {};
#pragma unroll
    for (int mt = 0; mt < 4; ++mt)
#pragma unroll
        for (int dt = 0; dt < 2; ++dt)
#pragma unroll
            for (int ks = 0; ks < 2; ++ks)
                o[mt][dt] = __builtin_amdgcn_mfma_f32_16x16x32_bf16(
                    pa[mt][ks], vb[dt][ks], o[mt][dt], 0, 0, 0);

    const long obase = (long)b * NTOK * CDIM + hq * 128 + w * 32;
#pragma unroll
    for (int mt = 0; mt < 4; ++mt)
#pragma unroll
        for (int r = 0; r < 4; ++r) {
            const int q = mt * 16 + quad4 + r;
            if (q < NTOK) {
                const long rb = obase + (long)q * CDIM;
#pragma unroll
                for (int dt = 0; dt < 2; ++dt)
                    out[rb + dt * 16 + l16] = __float2bfloat16(o[mt][dt][r]);
            }
        }
}

// ---------------------------------------------------------------------------
extern "C" void kernel_launch(void* const* d_in, const int* in_sizes, int n_in,
                              void* d_out, int out_size, void* d_ws, size_t ws_size,
                              hipStream_t stream) {
    const float* x          = (const float*)d_in[0];
    const float* mask       = (const float*)d_in[1];
    const float* qkv_w      = (const float*)d_in[2];
    const float* qkv_b      = (const float*)d_in[3];
    const float* proj_w     = (const float*)d_in[4];
    const float* proj_b     = (const float*)d_in[5];
    const float* bias_table = (const float*)d_in[6];

    char* ws = (char*)d_ws;
    __hip_bfloat16* xb   = (__hip_bfloat16*)(ws);
    __hip_bfloat16* qw   = (__hip_bfloat16*)(ws + 102760448);
    __hip_bfloat16* pw   = (__hip_bfloat16*)(ws + 104333312);
    __hip_bfloat16* qkvb = (__hip_bfloat16*)(ws + 104857600);
    __hip_bfloat16* ao   = xb;  // attn out reuses x_bf16 (GEMM1 done by then)

    static int attr_done = 0;
    if (!attr_done) {
        hipFuncSetAttribute(
            reinterpret_cast<const void*>(&gemm256<__hip_bfloat16>),
            hipFuncAttributeMaxDynamicSharedMemorySize, 131072);
        hipFuncSetAttribute(
            reinterpret_cast<const void*>(&gemm256<float>),
            hipFuncAttributeMaxDynamicSharedMemorySize, 131072);
        attr_done = 1;
    }

    cvt_f32_bf16<<<32768, 256, 0, stream>>>(x, xb, (MROWS * CDIM) / 4);
    cvt_f32_bf16<<<768,   256, 0, stream>>>(qkv_w, qw, (QKVN * CDIM) / 4);
    cvt_f32_bf16<<<256,   256, 0, stream>>>(proj_w, pw, (CDIM * CDIM) / 4);

    // qkv: M=100352, N=1536, K=512 -> 392*6 = 2352 blocks (%8==0)
    gemm256<__hip_bfloat16><<<2352, 512, 131072, stream>>>(
        xb, qw, qkv_b, qkvb, MROWS, QKVN, CDIM, 6, 294);

    attn_mfma<<<B_TOT * 4, 256, 0, stream>>>(qkvb, mask, bias_table, ao);

    // proj: M=100352, N=512, K=512 -> 392*2 = 784 blocks (%8==0)
    gemm256<float><<<784, 512, 131072, stream>>>(
        ao, pw, proj_b, (float*)d_out, MROWS, CDIM, CDIM, 2, 98);
}